// Round 8
// baseline (166.600 us; speedup 1.0000x reference)
//
#include <hip/hip_runtime.h>

#define B_    4
#define N_    20000
#define M_    20000
#define K_    16
#define CIN   64
#define CMID  16
#define COUT  67            // CIN + 3 additional channels
#define PPB   4             // one point per wave, 4 waves per block
#define LSTR  17            // padded LDS transpose stride (f32)
#define NXCD  8

typedef float float4_ __attribute__((ext_vector_type(4)));

__global__ __launch_bounds__(256, 6) void pconv_kernel(
    const float* __restrict__ in_feats,   // [B, N, 64]
    const int*   __restrict__ inds,       // [B, M, 16]
    const float* __restrict__ wn,         // [B, M, 16, 16]
    const float* __restrict__ addl,       // [B, M, 16, 3]
    float*       __restrict__ out)        // [B, M, 1072]
{
    __shared__ float lds_out[PPB][(COUT + 1) * LSTR];   // 4 x 4624 B transpose buf
    __shared__ float lds_wn [PPB][K_ * CMID];           // 4 x 1 KB (tail phase only)

    const int tid  = threadIdx.x;
    const int lane = tid & 63;
    const int wav  = tid >> 6;

    // bijective XCD swizzle: 20000 blocks -> 2500 contiguous per XCD slot
    const int qx  = gridDim.x / NXCD;                    // 2500
    const int swz = (blockIdx.x % NXCD) * qx + blockIdx.x / NXCD;

    const int bp = __builtin_amdgcn_readfirstlane(swz * PPB + wav);
    const int b  = bp / M_;

    const int*   pinds = inds + (long)bp * K_;
    const float* pwn   = wn   + (long)bp * (K_ * CMID);
    const float* padd  = addl + (long)bp * (K_ * 3);
    const float* bfeat = in_feats + (long)b * N_ * CIN;

    // ---- wn vector load for the tail-phase LDS copy (issued early) ----
    float4_ wstage = ((const float4_*)pwn)[lane];

    // ---- 16 neighbor indices -> SGPRs ----
    int idxs[K_];
    #pragma unroll
    for (int k = 0; k < K_; ++k) idxs[k] = pinds[k];

    // ---- issue ALL 16 gathers before any consumption (one L2 round-trip) ----
    float f[K_];
    #pragma unroll
    for (int k = 0; k < K_; ++k)
        f[k] = bfeat[(long)idxs[k] * CIN + lane];        // 256B coalesced each

    // stage wn to LDS for the tail phase
    *(float4_*)(&lds_wn[wav][lane * 4]) = wstage;

    // ---- FMA phase: lane owns channel c = lane ----
    // wn operands are wave-uniform -> SGPR s_loads on the scalar pipe
    // (no LDS traffic on the FMA critical path; SMEM prefetches ahead of VALU)
    float acc[CMID];
    #pragma unroll
    for (int w = 0; w < CMID; ++w) acc[w] = 0.f;

    #pragma unroll
    for (int k = 0; k < K_; ++k) {
        #pragma unroll
        for (int w = 0; w < CMID; ++w)
            acc[w] += f[k] * pwn[k * CMID + w];          // v_fmac vgpr,sgpr,vgpr
    }

    // ---- transpose via padded LDS (17-f32 stride: <=2-way banks, free) ----
    float* lo = &lds_out[wav][0];
    #pragma unroll
    for (int w = 0; w < CMID; ++w)
        lo[lane * LSTR + w] = acc[w];

    // tail channels c = 64+t (t=lane>>4, wt=lane&15), lanes 0..47
    const int t  = lane >> 4;
    const int wt = lane & 15;
    if (lane < 48) {
        float acc2 = 0.f;
        #pragma unroll
        for (int k = 0; k < K_; ++k) {
            float a0 = padd[k * 3 + 0];                  // uniform s_loads
            float a1 = padd[k * 3 + 1];
            float a2 = padd[k * 3 + 2];
            float av = (t == 0) ? a0 : (t == 1) ? a1 : a2;
            acc2 += av * lds_wn[wav][k * CMID + wt];     // 16 banks, 3-way broadcast
        }
        lo[(CIN + t) * LSTR + wt] = acc2;
    }

    // ---- readback in store-contiguous order; stores 4x1KB + 192B ----
    float* pout = out + (long)bp * (COUT * CMID);
    const int q = lane >> 2;
    const int r = lane & 3;
    #pragma unroll
    for (int p = 0; p < 4; ++p) {
        const float* src = lo + (p * 16 + q) * LSTR + 4 * r;
        float4_ v = { src[0], src[1], src[2], src[3] };
        *(float4_*)(pout + p * 256 + lane * 4) = v;
    }
    if (lane < 12) {
        const float* src = lo + (CIN + q) * LSTR + 4 * r;
        float4_ v = { src[0], src[1], src[2], src[3] };
        *(float4_*)(pout + 1024 + lane * 4) = v;
    }
}

extern "C" void kernel_launch(void* const* d_in, const int* in_sizes, int n_in,
                              void* d_out, int out_size, void* d_ws, size_t ws_size,
                              hipStream_t stream) {
    const float* in_feats = (const float*)d_in[0];
    const int*   ninds    = (const int*)d_in[1];
    const float* wn       = (const float*)d_in[2];
    const float* addl     = (const float*)d_in[3];
    float*       out      = (float*)d_out;

    const int total_points = B_ * M_;            // 80000
    dim3 grid(total_points / PPB);               // 20000 blocks, 1 point/wave
    dim3 block(256);
    pconv_kernel<<<grid, block, 0, stream>>>(in_feats, ninds, wn, addl, out);
}

// Round 9
// 141.476 us; speedup vs baseline: 1.1776x; 1.1776x over previous
//
#include <hip/hip_runtime.h>
#include <hip/hip_bf16.h>

#define B_    4
#define N_    20000
#define M_    20000
#define K_    16
#define CIN   64
#define CMID  16
#define COUT  67            // CIN + 3 additional channels
#define PPB   4             // one point per wave, 4 waves per block
#define NXCD  8

typedef float float4_ __attribute__((ext_vector_type(4)));
typedef short short8_ __attribute__((ext_vector_type(8)));

static __device__ __forceinline__ unsigned pk2(float lo, float hi) {
    // two RNE f32->bf16 converts packed into one dword (compiler emits v_cvt[_pk]_bf16_f32)
    unsigned short l = __builtin_bit_cast(unsigned short, __float2bfloat16(lo));
    unsigned short h = __builtin_bit_cast(unsigned short, __float2bfloat16(hi));
    return (unsigned)l | ((unsigned)h << 16);
}

static __device__ __forceinline__ short8_ mk8(unsigned p0, unsigned p1,
                                              unsigned p2, unsigned p3) {
    union { unsigned u[4]; short8_ s; } x;
    x.u[0] = p0; x.u[1] = p1; x.u[2] = p2; x.u[3] = p3;
    return x.s;
}

__global__ __launch_bounds__(256, 4) void pconv_kernel(
    const float* __restrict__ in_feats,   // [B, N, 64]
    const int*   __restrict__ inds,       // [B, M, 16]
    const float* __restrict__ wn,         // [B, M, 16, 16]
    const float* __restrict__ addl,       // [B, M, 16, 3]
    float*       __restrict__ out)        // [B, M, 1072]
{
    const int tid  = threadIdx.x;
    const int lane = tid & 63;
    const int wav  = tid >> 6;
    const int n16  = lane & 15;           // m (A row) / n (B,D col) within tile
    const int hi   = lane >> 4;           // k-group 0..3

    // bijective XCD swizzle: 20000 blocks -> 2500 contiguous per XCD slot
    const int qx  = gridDim.x / NXCD;
    const int swz = (blockIdx.x % NXCD) * qx + blockIdx.x / NXCD;

    const int bp = __builtin_amdgcn_readfirstlane(swz * PPB + wav);
    const int b  = bp / M_;

    const int*   pinds = inds + (long)bp * K_;
    const float* pwn   = wn   + (long)bp * (K_ * CMID);
    const float* padd  = addl + (long)bp * (K_ * 3);
    const float* bfeat = in_feats + (long)b * N_ * CIN;

    // ---- 16 neighbor indices -> SGPRs ----
    int idxs[K_];
    #pragma unroll
    for (int k = 0; k < K_; ++k) idxs[k] = pinds[k];

    // Fragment k-slot for element j of this lane: k = (hi*8 + j) & 15.
    // k>=16 slots (hi>=2) wrap to safe duplicates in A; B zeroes them, so the
    // MFMA dot-product sums exactly k=0..15. A/B share the slot map, and the
    // k-sum is permutation-invariant -> no dependence on the HW's internal
    // slot->k order. Only D's layout matters (HW-verified: col=lane&15,
    // row=(lane>>4)*4+reg).

    // ---- issue ALL loads up-front (48 independent dwords: max MLP) ----
    float afm[4][8];                       // A-main: 4 c-tiles x 8 k-slots
    #pragma unroll
    for (int t = 0; t < 4; ++t) {
        #pragma unroll
        for (int j = 0; j < 8; ++j) {
            const int k = (hi * 8 + j) & 15;
            afm[t][j] = bfeat[(long)idxs[k] * CIN + t * 16 + n16];  // 2x64B granules/instr
        }
    }
    float bwv[8];                          // B: wn[k][n]
    #pragma unroll
    for (int j = 0; j < 8; ++j) {
        const int k = (hi * 8 + j) & 15;
        bwv[j] = pwn[k * CMID + n16];
    }
    float atv[8];                          // A-tail: addl[k][m], m clamped (rows>=3 unused)
    const int mcl = (n16 < 3) ? n16 : 2;
    #pragma unroll
    for (int j = 0; j < 8; ++j) {
        const int k = (hi * 8 + j) & 15;
        atv[j] = padd[k * 3 + mcl];
    }

    // ---- pack to bf16 fragments ----
    short8_ afrag[4];
    #pragma unroll
    for (int t = 0; t < 4; ++t)
        afrag[t] = mk8(pk2(afm[t][0], afm[t][1]), pk2(afm[t][2], afm[t][3]),
                       pk2(afm[t][4], afm[t][5]), pk2(afm[t][6], afm[t][7]));

    const bool realk = hi < 2;             // k-slots 0..15 real, 16..31 zero
    short8_ bfrag = mk8(realk ? pk2(bwv[0], bwv[1]) : 0u,
                        realk ? pk2(bwv[2], bwv[3]) : 0u,
                        realk ? pk2(bwv[4], bwv[5]) : 0u,
                        realk ? pk2(bwv[6], bwv[7]) : 0u);
    short8_ tfrag = mk8(pk2(atv[0], atv[1]), pk2(atv[2], atv[3]),
                        pk2(atv[4], atv[5]), pk2(atv[6], atv[7]));

    // ---- 5 MFMAs: D[c][w] tiles (c-tiles 0..3 main, 4 = tail channels) ----
    float4_ zero = (float4_)0.f;
    float4_ acc[5];
    #pragma unroll
    for (int t = 0; t < 4; ++t)
        acc[t] = __builtin_amdgcn_mfma_f32_16x16x32_bf16(afrag[t], bfrag, zero, 0, 0, 0);
    acc[4] = __builtin_amdgcn_mfma_f32_16x16x32_bf16(tfrag, bfrag, zero, 0, 0, 0);

    // ---- direct stores: D[row=hi*4+r][col=n16] -> out[bp][c][w] ----
    // per instr: 4 rows x 64B = 4 full granules, stride 256B -> no RMW
    float* pout = out + (long)bp * (COUT * CMID);
    #pragma unroll
    for (int t = 0; t < 4; ++t) {
        #pragma unroll
        for (int r = 0; r < 4; ++r)
            pout[(t * 16 + hi * 4 + r) * CMID + n16] = acc[t][r];
    }
    if (lane < 16) {                       // tail rows 0..2 = channels 64..66
        #pragma unroll
        for (int r = 0; r < 3; ++r)
            pout[(CIN + r) * CMID + n16] = acc[4][r];
    }
}

extern "C" void kernel_launch(void* const* d_in, const int* in_sizes, int n_in,
                              void* d_out, int out_size, void* d_ws, size_t ws_size,
                              hipStream_t stream) {
    const float* in_feats = (const float*)d_in[0];
    const int*   ninds    = (const int*)d_in[1];
    const float* wnp      = (const float*)d_in[2];
    const float* addl     = (const float*)d_in[3];
    float*       outp     = (float*)d_out;

    const int total_points = B_ * M_;            // 80000
    dim3 grid(total_points / PPB);               // 20000 blocks, 1 point/wave
    dim3 block(256);
    pconv_kernel<<<grid, block, 0, stream>>>(in_feats, ninds, wnp, addl, outp);
}

// Round 10
// 139.581 us; speedup vs baseline: 1.1936x; 1.0136x over previous
//
#include <hip/hip_runtime.h>
#include <hip/hip_bf16.h>

#define B_    4
#define N_    20000
#define M_    20000
#define K_    16
#define CIN   64
#define CMID  16
#define COUT  67            // CIN + 3 additional channels
#define PPB   4             // one point per wave, 4 waves per block
#define NXCD  8

typedef float float4_ __attribute__((ext_vector_type(4)));
typedef short short8_ __attribute__((ext_vector_type(8)));

static __device__ __forceinline__ unsigned pk2(float lo, float hi) {
    unsigned short l = __builtin_bit_cast(unsigned short, __float2bfloat16(lo));
    unsigned short h = __builtin_bit_cast(unsigned short, __float2bfloat16(hi));
    return (unsigned)l | ((unsigned)h << 16);
}

static __device__ __forceinline__ short8_ mk8(unsigned p0, unsigned p1,
                                              unsigned p2, unsigned p3) {
    union { unsigned u[4]; short8_ s; } x;
    x.u[0] = p0; x.u[1] = p1; x.u[2] = p2; x.u[3] = p3;
    return x.s;
}

__global__ __launch_bounds__(256, 6) void pconv_kernel(
    const float* __restrict__ in_feats,   // [B, N, 64]
    const int*   __restrict__ inds,       // [B, M, 16]
    const float* __restrict__ wn,         // [B, M, 16, 16]
    const float* __restrict__ addl,       // [B, M, 16, 3]
    float*       __restrict__ out)        // [B, M, 1072]
{
    const int tid  = threadIdx.x;
    const int lane = tid & 63;
    const int wav  = tid >> 6;
    const int n16  = lane & 15;           // m (A row) / n (B,D col) within tile
    const int hi   = lane >> 4;           // k-group 0..3

    // bijective XCD swizzle: 20000 blocks -> 2500 contiguous per XCD slot
    const int qx  = gridDim.x / NXCD;
    const int swz = (blockIdx.x % NXCD) * qx + blockIdx.x / NXCD;

    const int bp = __builtin_amdgcn_readfirstlane(swz * PPB + wav);
    const int b  = bp / M_;

    const int*   pinds = inds + (long)bp * K_;
    const float* pwn   = wn   + (long)bp * (K_ * CMID);
    const float* padd  = addl + (long)bp * (K_ * 3);
    const float* bfeat = in_feats + (long)b * N_ * CIN;

    // ---- 16 neighbor indices -> SGPRs ----
    int idxs[K_];
    #pragma unroll
    for (int k = 0; k < K_; ++k) idxs[k] = pinds[k];

    // Fragment k-slot map: element j of this lane covers k = (hi*8 + j) & 15.
    // hi>=2 wraps onto duplicates in A; B zeroes those slots, so the MFMA
    // sums exactly k=0..15. A and B share the slot map and the k-sum is
    // permutation-invariant; only D's layout matters (HW-verified:
    // col=lane&15, row=(lane>>4)*4+reg).

    // ---- B and tail-A fragments first (short-lived f32, packed promptly) ----
    float bwv[8];
    #pragma unroll
    for (int j = 0; j < 8; ++j) {
        const int k = (hi * 8 + j) & 15;
        bwv[j] = pwn[k * CMID + n16];
    }
    float atv[8];
    const int mcl = (n16 < 3) ? n16 : 2;          // rows >=3 of tail tile unused
    #pragma unroll
    for (int j = 0; j < 8; ++j) {
        const int k = (hi * 8 + j) & 15;
        atv[j] = padd[k * 3 + mcl];
    }

    const bool realk = hi < 2;                    // k-slots 16..31 are zero in B
    short8_ bfrag = mk8(realk ? pk2(bwv[0], bwv[1]) : 0u,
                        realk ? pk2(bwv[2], bwv[3]) : 0u,
                        realk ? pk2(bwv[4], bwv[5]) : 0u,
                        realk ? pk2(bwv[6], bwv[7]) : 0u);
    short8_ tfrag = mk8(pk2(atv[0], atv[1]), pk2(atv[2], atv[3]),
                        pk2(atv[4], atv[5]), pk2(atv[6], atv[7]));

    // ---- A-main: 4 c-tiles x 8 k-slots; load + pack per tile ----
    float afm[4][8];
    #pragma unroll
    for (int t = 0; t < 4; ++t) {
        #pragma unroll
        for (int j = 0; j < 8; ++j) {
            const int k = (hi * 8 + j) & 15;
            afm[t][j] = bfeat[(long)idxs[k] * CIN + t * 16 + n16];  // 2x64B granules
        }
    }
    short8_ afrag[4];
    #pragma unroll
    for (int t = 0; t < 4; ++t)
        afrag[t] = mk8(pk2(afm[t][0], afm[t][1]), pk2(afm[t][2], afm[t][3]),
                       pk2(afm[t][4], afm[t][5]), pk2(afm[t][6], afm[t][7]));

    // ---- 5 MFMAs ----
    float4_ zero = (float4_)0.f;
    float4_ acc[5];
    #pragma unroll
    for (int t = 0; t < 4; ++t)
        acc[t] = __builtin_amdgcn_mfma_f32_16x16x32_bf16(afrag[t], bfrag, zero, 0, 0, 0);
    acc[4] = __builtin_amdgcn_mfma_f32_16x16x32_bf16(tfrag, bfrag, zero, 0, 0, 0);

    // ---- direct stores: D[row=hi*4+r][col=n16]; each instr covers 4 full 64B granules ----
    float* pout = out + (long)bp * (COUT * CMID);
    #pragma unroll
    for (int t = 0; t < 4; ++t) {
        #pragma unroll
        for (int r = 0; r < 4; ++r)
            pout[(t * 16 + hi * 4 + r) * CMID + n16] = acc[t][r];
    }
    if (lane < 16) {                       // tail rows 0..2 = channels 64..66
        #pragma unroll
        for (int r = 0; r < 3; ++r)
            pout[(CIN + r) * CMID + n16] = acc[4][r];
    }
}

extern "C" void kernel_launch(void* const* d_in, const int* in_sizes, int n_in,
                              void* d_out, int out_size, void* d_ws, size_t ws_size,
                              hipStream_t stream) {
    const float* in_feats = (const float*)d_in[0];
    const int*   ninds    = (const int*)d_in[1];
    const float* wnp      = (const float*)d_in[2];
    const float* addl     = (const float*)d_in[3];
    float*       outp     = (float*)d_out;

    const int total_points = B_ * M_;            // 80000
    dim3 grid(total_points / PPB);               // 20000 blocks, 1 point/wave
    dim3 block(256);
    pconv_kernel<<<grid, block, 0, stream>>>(in_feats, ninds, wnp, addl, outp);
}